// Round 10
// baseline (132.701 us; speedup 1.0000x reference)
//
#include <hip/hip_runtime.h>
#include <hip/hip_bf16.h>

#define N 8192
#define D 256
#define NSLICE 32
#define BM 256                          // rows per block (4 waves x 64 rows)
#define TROWS 4                         // row-tiles of 16 per wave
#define CSTRIP 16                       // cols per register strip
#define COLS_PER_SLICE (N / NSLICE)     // 256
#define NSTRIP (COLS_PER_SLICE / CSTRIP)  // 16
#define NRB (N / BM)                    // 32 row blocks

#define CSHIFT 160.0f                   // fixed base-2 LSE shift
#define K2LOG2E 2.885390082f            // (1/T) * log2(e) = 2 * 1.44269504
#define LN2F 0.6931471805599453f

typedef __attribute__((ext_vector_type(8))) short bf16x8;
typedef __attribute__((ext_vector_type(4))) float f32x4;

__device__ inline float fast_exp2(float x) { return __builtin_amdgcn_exp2f(x); }
__device__ inline float fast_log2(float x) { return __builtin_amdgcn_logf(x); }

__device__ inline ushort f2bf(float x) {
    __hip_bfloat16 h = __float2bfloat16(x);
    return *reinterpret_cast<ushort*>(&h);
}

// ---------------- kernel 0: fp32 -> bf16 conversion ----------------
__global__ void convert_bf16(const float* __restrict__ F, const float* __restrict__ Imp,
                             ushort* __restrict__ Fb, ushort* __restrict__ Ib) {
    const int i = blockIdx.x * blockDim.x + threadIdx.x;  // float4 index
    const int total4 = N * D / 4;
    const float4* src = (blockIdx.y == 0) ? (const float4*)F : (const float4*)Imp;
    ushort* dst = (blockIdx.y == 0) ? Fb : Ib;
    if (i < total4) {
        float4 v = src[i];
        ushort4 o;
        o.x = f2bf(v.x); o.y = f2bf(v.y); o.z = f2bf(v.z); o.w = f2bf(v.w);
        *reinterpret_cast<ushort4*>(dst + 4 * (size_t)i) = o;
    }
}

// ---------------- kernel 0b: label histogram (14 bins) ----------------
__global__ void label_hist(const int* __restrict__ labels, int* __restrict__ counts) {
    __shared__ int c[16];
    if (threadIdx.x < 16) c[threadIdx.x] = 0;
    __syncthreads();
    for (int i = threadIdx.x; i < N; i += blockDim.x) atomicAdd(&c[labels[i]], 1);
    __syncthreads();
    if (threadIdx.x < 16) counts[threadIdx.x] = c[threadIdx.x];
}

// ---------------- kernel 1: register-streaming tile kernel ----------------
// No B LDS staging (per-strip B slice is 8KB -> L1-resident, shared by the 4
// waves and the co-resident block on the same slice). No main-loop barriers:
// waves free-run; B double-buffered in registers; A fragments PINNED in
// registers via asm (prevents the compiler from sinking the loads into the
// loop, which r7-r9's VGPR_Count=116..128 proved it was doing).
// blockIdx.x: row block (256 rows), blockIdx.y: column slice (256 cols).
__launch_bounds__(256, 2)
__global__ void tile_pass(const ushort* __restrict__ Fb, const ushort* __restrict__ Ib,
                          const int* __restrict__ labels,
                          float* __restrict__ partials_row,    // [N][NSLICE]
                          float* __restrict__ partials_col) {  // [NRB][N]
    __shared__ float colacc[4][COLS_PER_SLICE];     // 4KB, per-wave private rows
    __shared__ int labs[COLS_PER_SLICE];            // 1KB

    const int tid = threadIdx.x;
    const int lane = tid & 63;
    const int wave = tid >> 6;
    const int rb = blockIdx.x;
    const int row0 = rb * BM + wave * (16 * TROWS); // 4 row-tiles of 16
    const int c0 = blockIdx.y * COLS_PER_SLICE;
    const int lrow = lane & 15;                     // A-row / B-col within tile
    const int kgrp = lane >> 4;                     // 0..3

    for (int i = tid; i < COLS_PER_SLICE; i += 256) {
        labs[i] = labels[c0 + i];
        colacc[0][i] = 0.f; colacc[1][i] = 0.f; colacc[2][i] = 0.f; colacc[3][i] = 0.f;
    }

    // A fragments, register-resident for the whole kernel (4 tiles x K=256)
    bf16x8 afrag[TROWS][8];
#pragma unroll
    for (int t = 0; t < TROWS; ++t) {
        const ushort* arow = Fb + (size_t)(row0 + t * 16 + lrow) * D;
#pragma unroll
        for (int ks = 0; ks < 8; ++ks)
            afrag[t][ks] = *reinterpret_cast<const bf16x8*>(arow + ks * 32 + kgrp * 8);
    }
    // PIN: make afrag asm-defined so the compiler cannot rematerialize the
    // loads inside the loop (r7-r9 showed it re-loads from global otherwise).
#pragma unroll
    for (int t = 0; t < TROWS; ++t)
#pragma unroll
        for (int ks = 0; ks < 8; ++ks)
            asm volatile("" : "+v"(afrag[t][ks]));

    // my output rows' labels, packed 4x8 bits per row-tile (labels are 0..13)
    int labp[TROWS];
#pragma unroll
    for (int t = 0; t < TROWS; ++t) {
        const int base = row0 + t * 16 + kgrp * 4;
        labp[t] = labels[base] | (labels[base + 1] << 8) |
                  (labels[base + 2] << 16) | (labels[base + 3] << 24);
    }

    float s[TROWS][4];
#pragma unroll
    for (int t = 0; t < TROWS; ++t)
#pragma unroll
        for (int r = 0; r < 4; ++r) s[t][r] = 0.0f;

    __syncthreads();  // labs/colacc ready (the only pre-epilogue barrier)

    // B fragment base: strip st, slice ks -> bbase + st*16*D + ks*32
    const ushort* bbase = Ib + (size_t)(c0 + lrow) * D + kgrp * 8;

#define LOADB(buf, st)                                                          \
    {                                                                           \
        _Pragma("unroll")                                                       \
        for (int ks = 0; ks < 8; ++ks)                                          \
            buf[ks] = *reinterpret_cast<const bf16x8*>(                         \
                bbase + (size_t)(st) * (16 * D) + ks * 32);                     \
    }

#define COMPUTE(buf, st)                                                        \
    {                                                                           \
        const int labc = labs[(st) * CSTRIP + lrow];                            \
        f32x4 acc[TROWS];                                                       \
        _Pragma("unroll")                                                       \
        for (int t = 0; t < TROWS; ++t) acc[t] = f32x4{0.f, 0.f, 0.f, 0.f};     \
        _Pragma("unroll")                                                       \
        for (int ks = 0; ks < 8; ++ks)                                          \
            _Pragma("unroll")                                                   \
            for (int t = 0; t < TROWS; ++t)                                     \
                acc[t] = __builtin_amdgcn_mfma_f32_16x16x32_bf16(               \
                    afrag[t][ks], buf[ks], acc[t], 0, 0, 0);                    \
        float colpart = 0.0f;                                                   \
        _Pragma("unroll")                                                       \
        for (int t = 0; t < TROWS; ++t) {                                       \
            _Pragma("unroll")                                                   \
            for (int r = 0; r < 4; ++r) {                                       \
                float arg = __builtin_fmaf(acc[t][r], K2LOG2E, -CSHIFT);        \
                const int lr = (labp[t] >> (8 * r)) & 255;                      \
                arg = (lr == labc) ? -1000.0f : arg;                            \
                float e = fast_exp2(arg);                                       \
                s[t][r] += e;                                                   \
                colpart += e;                                                   \
            }                                                                   \
        }                                                                       \
        colpart += __shfl_xor(colpart, 16, 64);                                 \
        colpart += __shfl_xor(colpart, 32, 64);                                 \
        if (kgrp == 0) colacc[wave][(st) * CSTRIP + lrow] += colpart;           \
    }

    // register double-buffer, manual 2-step body (static indexing, rule #20)
    bf16x8 bA[8], bB[8];
    LOADB(bA, 0);
    for (int st = 0; st < NSTRIP; st += 2) {
        LOADB(bB, st + 1);                       // st+1 <= NSTRIP-1 (NSTRIP even)
        COMPUTE(bA, st);
        if (st + 2 < NSTRIP) LOADB(bA, st + 2);
        COMPUTE(bB, st + 1);
    }
#undef LOADB
#undef COMPUTE

    // row partials: sum the 16 lrow-lanes (disjoint column subsets)
#pragma unroll
    for (int off = 1; off < 16; off <<= 1) {
#pragma unroll
        for (int t = 0; t < TROWS; ++t)
#pragma unroll
            for (int r = 0; r < 4; ++r)
                s[t][r] += __shfl_xor(s[t][r], off, 64);
    }
    if (lrow == 0) {
#pragma unroll
        for (int t = 0; t < TROWS; ++t)
#pragma unroll
            for (int r = 0; r < 4; ++r) {
                const int grow = row0 + t * 16 + kgrp * 4 + r;
                partials_row[(size_t)grow * NSLICE + blockIdx.y] = s[t][r];
            }
    }

    __syncthreads();  // all colacc writes visible
    for (int i = tid; i < COLS_PER_SLICE; i += 256) {
        float v = colacc[0][i] + colacc[1][i] + colacc[2][i] + colacc[3][i];
        partials_col[(size_t)rb * N + c0 + i] = v;
    }
}

// ---------------- kernel 1b: reduce col partials over row blocks ----------------
__global__ void col_reduce(const float* __restrict__ partials_col, float* __restrict__ colsum) {
    const int c = blockIdx.x * 256 + threadIdx.x;
    float v = 0.0f;
    for (int rbi = 0; rbi < NRB; ++rbi) v += partials_col[(size_t)rbi * N + c];
    colsum[c] = v;
}

// exact lse over { S*2^CSHIFT (bulk), cnt*exp(0), exp(diag) }
__device__ inline float final_lse(float S, float cntlog, float diag) {
    float l1 = (S > 0.0f) ? (CSHIFT + fast_log2(S)) * LN2F : -INFINITY;
    float M = fmaxf(fmaxf(l1, cntlog), diag);  // M finite: diag always finite
    return M + __logf(__expf(l1 - M) + __expf(cntlog - M) + __expf(diag - M));
}

// ---------------- kernel 2: per-row contribution (wave per row) ----------------
__global__ void row_contrib(const float* __restrict__ F, const float* __restrict__ Imp,
                            const float* __restrict__ partials_row,
                            const float* __restrict__ colsum,
                            const int* __restrict__ counts,
                            const int* __restrict__ labels, float* __restrict__ blockSums) {
    const int lane = threadIdx.x & 63;
    const int wave = threadIdx.x >> 6;
    const int row = blockIdx.x * 4 + wave;

    // fp32 diagonal dot: 256 floats = 64 lanes * float4
    float4 a = reinterpret_cast<const float4*>(F + (size_t)row * D)[lane];
    float4 b = reinterpret_cast<const float4*>(Imp + (size_t)row * D)[lane];
    float dot = a.x * b.x + a.y * b.y + a.z * b.z + a.w * b.w;
#pragma unroll
    for (int off = 32; off > 0; off >>= 1) dot += __shfl_xor(dot, off, 64);

    __shared__ float sums[4];
    if (lane == 0) {
        const float diag = 2.0f * dot;                 // temperature 0.5
        const int cnt = counts[labels[row]] - 1;       // equal-label count excl. self
        const float cntlog = (cnt > 0) ? __logf((float)cnt) : -INFINITY;
        float S_row = 0.0f;
#pragma unroll
        for (int k = 0; k < NSLICE; ++k) S_row += partials_row[(size_t)row * NSLICE + k];
        const float S_col = colsum[row];
        const float lse_total = final_lse(S_row, cntlog, diag) + final_lse(S_col, cntlog, diag);
        sums[wave] = 2.0f * diag - lse_total;
    }
    __syncthreads();
    if (threadIdx.x == 0)
        blockSums[blockIdx.x] = sums[0] + sums[1] + sums[2] + sums[3];
}

// ---------------- kernel 3: final deterministic reduce ----------------
__global__ void final_reduce(const float* __restrict__ blockSums, float* __restrict__ out) {
    __shared__ float red[256];
    float v = 0.0f;
    for (int i = threadIdx.x; i < N / 4; i += 256) v += blockSums[i];
    red[threadIdx.x] = v;
    __syncthreads();
    for (int st = 128; st > 0; st >>= 1) {
        if (threadIdx.x < st) red[threadIdx.x] += red[threadIdx.x + st];
        __syncthreads();
    }
    if (threadIdx.x == 0) out[0] = -red[0] / (float)N;
}

extern "C" void kernel_launch(void* const* d_in, const int* in_sizes, int n_in,
                              void* d_out, int out_size, void* d_ws, size_t ws_size,
                              hipStream_t stream) {
    const float* F = (const float*)d_in[0];
    const float* Imp = (const float*)d_in[1];
    const int* labels = (const int*)d_in[2];
    float* out = (float*)d_out;

    char* ws = (char*)d_ws;
    size_t off = 0;
    ushort* Fb = (ushort*)(ws + off); off += (size_t)N * D * 2;               // 4 MB
    ushort* Ib = (ushort*)(ws + off); off += (size_t)N * D * 2;               // 4 MB
    float* partials_row = (float*)(ws + off); off += (size_t)N * NSLICE * 4;  // 1 MB
    float* partials_col = (float*)(ws + off); off += (size_t)NRB * N * 4;     // 1 MB
    float* colsum = (float*)(ws + off); off += (size_t)N * 4;                 // 32 KB
    float* blockSums = (float*)(ws + off); off += (size_t)(N / 4) * 4;        // 8 KB
    int* counts = (int*)(ws + off);

    dim3 cgrid((N * D / 4 + 255) / 256, 2);
    convert_bf16<<<cgrid, 256, 0, stream>>>(F, Imp, Fb, Ib);
    label_hist<<<1, 256, 0, stream>>>(labels, counts);

    dim3 g(NRB, NSLICE);
    tile_pass<<<g, 256, 0, stream>>>(Fb, Ib, labels, partials_row, partials_col);

    col_reduce<<<N / 256, 256, 0, stream>>>(partials_col, colsum);
    row_contrib<<<N / 4, 256, 0, stream>>>(F, Imp, partials_row, colsum, counts, labels, blockSums);
    final_reduce<<<1, 256, 0, stream>>>(blockSums, out);
}

// Round 11
// 68.325 us; speedup vs baseline: 1.9422x; 1.9422x over previous
//
#include <hip/hip_runtime.h>
#include <hip/hip_bf16.h>

#define N 8192
#define D 256
#define NSLICE 32
#define BM 256                          // rows per block (4 waves x 64 rows)
#define TROWS 4                         // row-tiles of 16 per wave
#define CB 32                           // cols per staged LDS tile
#define COLS_PER_SLICE (N / NSLICE)     // 256... (N/NSLICE)=256
#define NT (COLS_PER_SLICE / CB)        // 8 tiles per block
#define NRB (N / BM)                    // 32 row blocks
#define TILE_B (CB * D)                 // 8192 bytes per fp8 tile

#define CSHIFT 160.0f                   // fixed base-2 LSE shift
#define K2LOG2E 2.885390082f            // (1/T) * log2(e) = 2 * 1.44269504
#define LN2F 0.6931471805599453f

typedef __attribute__((ext_vector_type(4))) float f32x4;

__device__ inline float fast_exp2(float x) { return __builtin_amdgcn_exp2f(x); }
__device__ inline float fast_log2(float x) { return __builtin_amdgcn_logf(x); }

// async global->LDS, 16B per lane; LDS dest = wave-uniform base + lane*16.
__device__ inline void gload_lds16(const void* g, void* l) {
    __builtin_amdgcn_global_load_lds(
        (const __attribute__((address_space(1))) void*)g,
        (__attribute__((address_space(3))) void*)l, 16, 0, 0);
}

// pack 4 fp32 -> 4 fp8 e4m3 bytes (OCP on gfx950)
__device__ inline unsigned int pack_fp8x4(float a, float b, float c, float d) {
    unsigned int p = __builtin_amdgcn_cvt_pk_fp8_f32(a, b, 0, 0);    // bytes 0-1
    p = __builtin_amdgcn_cvt_pk_fp8_f32(c, d, (int)p, 1);            // bytes 2-3
    return p;
}

// ---------------- kernel 0: fp32 -> fp8 conversion ----------------
// y==0: F row-major fp8 (read directly to regs in tile_pass)
// y==1: I in FRAGMENT order: byte b -> col=(b>>12)*16+((b>>3)&15),
//       k=((b>>9)&7)*32+((b>>6)&3)*8+(b&7)  (16-col group / ks / lane / j)
// so that global_load_lds with LINEAR dest yields the MFMA fragment layout.
__global__ void convert_fp8(const float* __restrict__ F, const float* __restrict__ Imp,
                            unsigned int* __restrict__ Fb8, unsigned int* __restrict__ Ib8) {
    const int i = blockIdx.x * blockDim.x + threadIdx.x;  // 8 bytes per thread
    if (blockIdx.y == 0) {
        // row-major: fp8 linear order == fp32 linear order
        const float4 v0 = reinterpret_cast<const float4*>(F)[i * 2];
        const float4 v1 = reinterpret_cast<const float4*>(F)[i * 2 + 1];
        Fb8[i * 2] = pack_fp8x4(v0.x, v0.y, v0.z, v0.w);
        Fb8[i * 2 + 1] = pack_fp8x4(v1.x, v1.y, v1.z, v1.w);
    } else {
        const int lane = i & 63;
        const int ks = (i >> 6) & 7;
        const int g = i >> 9;
        const int col = g * 16 + (lane & 15);
        const int k0 = ks * 32 + (lane >> 4) * 8;
        const float* src = Imp + (size_t)col * D + k0;
        const float4 v0 = *reinterpret_cast<const float4*>(src);
        const float4 v1 = *reinterpret_cast<const float4*>(src + 4);
        Ib8[i * 2] = pack_fp8x4(v0.x, v0.y, v0.z, v0.w);
        Ib8[i * 2 + 1] = pack_fp8x4(v1.x, v1.y, v1.z, v1.w);
    }
}

// ---------------- kernel 0b: label histogram (14 bins) ----------------
__global__ void label_hist(const int* __restrict__ labels, int* __restrict__ counts) {
    __shared__ int c[16];
    if (threadIdx.x < 16) c[threadIdx.x] = 0;
    __syncthreads();
    for (int i = threadIdx.x; i < N; i += blockDim.x) atomicAdd(&c[labels[i]], 1);
    __syncthreads();
    if (threadIdx.x < 16) counts[threadIdx.x] = c[threadIdx.x];
}

// ---------------- kernel 1: fp8 single-pass tile kernel ----------------
// fp8 e4m3 both operands (non-scaled MFMA = bf16 rate, half the regs/LDS):
// afrag = 64 VGPRs (vs 128 bf16) -> fits under the 128-reg wall that made
// the compiler sink/spill A in r7-r10. LDS tile 8KB; ds_read_b64 fragments.
// Triple-buffer, one counted-vmcnt + one s_barrier per tile (r7 schedule).
// blockIdx.x: row block (256 rows), blockIdx.y: column slice (256 cols).
__launch_bounds__(256, 2)
__global__ void tile_pass(const unsigned char* __restrict__ Fb8,
                          const unsigned char* __restrict__ Ib8,
                          const int* __restrict__ labels,
                          float* __restrict__ partials_row,    // [N][NSLICE]
                          float* __restrict__ partials_col) {  // [NRB][N]
    __shared__ __align__(16) unsigned char Bsh[3 * TILE_B];  // 24KB
    __shared__ float colacc[4][COLS_PER_SLICE];              // 4KB
    __shared__ int labs[COLS_PER_SLICE];                     // 1KB

    const int tid = threadIdx.x;
    const int lane = tid & 63;
    const int wave = tid >> 6;
    const int rb = blockIdx.x;
    const int row0 = rb * BM + wave * (16 * TROWS);
    const int c0 = blockIdx.y * COLS_PER_SLICE;
    const int lrow = lane & 15;
    const int kgrp = lane >> 4;

    // stage one 32-col tile (8KB, fragment-ordered in GLOBAL memory already):
    // 8 chunks of 1KB; wave w stages chunks 2w, 2w+1; linear dest & src.
#define STAGE(buf, ct)                                                          \
    {                                                                           \
        const unsigned char* tbase = Ib8 + (size_t)(c0 + (ct) * CB) * D;        \
        _Pragma("unroll")                                                       \
        for (int i = 0; i < 2; ++i) {                                           \
            const int chunk = wave * 2 + i;                                     \
            gload_lds16(tbase + chunk * 1024 + lane * 16,                       \
                        &Bsh[(buf) * TILE_B + chunk * 1024 + lane * 16]);       \
        }                                                                       \
    }

    STAGE(0, 0);
    STAGE(1, 1);

    for (int i = tid; i < COLS_PER_SLICE; i += 256) {
        labs[i] = labels[c0 + i];
        colacc[0][i] = 0.f; colacc[1][i] = 0.f; colacc[2][i] = 0.f; colacc[3][i] = 0.f;
    }

    // A fragments fp8: 8 bytes/lane per (t,ks) = 2 VGPRs; 64 VGPRs total.
    long afrag[TROWS][8];
#pragma unroll
    for (int t = 0; t < TROWS; ++t) {
        const unsigned char* arow = Fb8 + (size_t)(row0 + t * 16 + lrow) * D;
#pragma unroll
        for (int ks = 0; ks < 8; ++ks)
            afrag[t][ks] = *reinterpret_cast<const long*>(arow + ks * 32 + kgrp * 8);
    }

    // my output rows' labels, packed 4x8 bits per row-tile (labels 0..13)
    int labp[TROWS];
#pragma unroll
    for (int t = 0; t < TROWS; ++t) {
        const int base = row0 + t * 16 + kgrp * 4;
        labp[t] = labels[base] | (labels[base + 1] << 8) |
                  (labels[base + 2] << 16) | (labels[base + 3] << 24);
    }

    float s[TROWS][4];
#pragma unroll
    for (int t = 0; t < TROWS; ++t)
#pragma unroll
        for (int r = 0; r < 4; ++r) s[t][r] = 0.0f;

    // tile 0 landed (2 loads of tile 1 may fly); labs/colacc visible
    asm volatile("s_waitcnt vmcnt(2) lgkmcnt(0)" ::: "memory");
    __builtin_amdgcn_s_barrier();

    int cbuf = 0, sbuf = 2;
    for (int ct = 0; ct < NT; ++ct) {
        if (ct + 2 < NT) STAGE(sbuf, ct + 2);  // keep 2 tiles in flight

        __builtin_amdgcn_s_setprio(1);
#pragma unroll
        for (int u = 0; u < 2; ++u) {
            long bfrag[8];
#pragma unroll
            for (int ks = 0; ks < 8; ++ks)
                bfrag[ks] = *reinterpret_cast<const long*>(
                    &Bsh[cbuf * TILE_B + (u * 8 + ks) * 512 + lane * 8]);  // linear

            const int labc = labs[ct * CB + u * 16 + lrow];
            float colpart = 0.0f;
            f32x4 acc[TROWS];
#pragma unroll
            for (int t = 0; t < TROWS; ++t) acc[t] = f32x4{0.f, 0.f, 0.f, 0.f};
#pragma unroll
            for (int ks = 0; ks < 8; ++ks)
#pragma unroll
                for (int t = 0; t < TROWS; ++t)
                    acc[t] = __builtin_amdgcn_mfma_f32_16x16x32_fp8_fp8(
                        afrag[t][ks], bfrag[ks], acc[t], 0, 0, 0);

#pragma unroll
            for (int t = 0; t < TROWS; ++t) {
                // D layout: col = lane&15, row = (lane>>4)*4 + r (dtype-indep)
#pragma unroll
                for (int r = 0; r < 4; ++r) {
                    float arg = __builtin_fmaf(acc[t][r], K2LOG2E, -CSHIFT);
                    const int lr = (labp[t] >> (8 * r)) & 255;
                    arg = (lr == labc) ? -1000.0f : arg;  // masked (incl. diag) -> 0
                    float e = fast_exp2(arg);
                    s[t][r] += e;
                    colpart += e;
                }
            }
            colpart += __shfl_xor(colpart, 16, 64);
            colpart += __shfl_xor(colpart, 32, 64);
            if (kgrp == 0)
                colacc[wave][ct * CB + u * 16 + lrow] += colpart;
        }
        __builtin_amdgcn_s_setprio(0);

        // counted wait: tile t+1 landed, tile t+2 stays in flight
        if (ct + 2 < NT) {
            asm volatile("s_waitcnt vmcnt(2)" ::: "memory");
        } else {
            asm volatile("s_waitcnt vmcnt(0)" ::: "memory");
        }
        __builtin_amdgcn_s_barrier();
        cbuf = (cbuf == 2) ? 0 : cbuf + 1;
        sbuf = (sbuf == 2) ? 0 : sbuf + 1;
    }

    // row partials: sum the 16 lrow-lanes (disjoint column subsets)
#pragma unroll
    for (int off = 1; off < 16; off <<= 1) {
#pragma unroll
        for (int t = 0; t < TROWS; ++t)
#pragma unroll
            for (int r = 0; r < 4; ++r)
                s[t][r] += __shfl_xor(s[t][r], off, 64);
    }
    if (lrow == 0) {
#pragma unroll
        for (int t = 0; t < TROWS; ++t)
#pragma unroll
            for (int r = 0; r < 4; ++r) {
                const int grow = row0 + t * 16 + kgrp * 4 + r;
                partials_row[(size_t)grow * NSLICE + blockIdx.y] = s[t][r];
            }
    }

    __syncthreads();  // all colacc writes visible
    for (int i = tid; i < COLS_PER_SLICE; i += 256) {
        float v = colacc[0][i] + colacc[1][i] + colacc[2][i] + colacc[3][i];
        partials_col[(size_t)rb * N + c0 + i] = v;
    }
#undef STAGE
}

// ---------------- kernel 1b: reduce col partials over row blocks ----------------
__global__ void col_reduce(const float* __restrict__ partials_col, float* __restrict__ colsum) {
    const int c = blockIdx.x * 256 + threadIdx.x;
    float v = 0.0f;
    for (int rbi = 0; rbi < NRB; ++rbi) v += partials_col[(size_t)rbi * N + c];
    colsum[c] = v;
}

// exact lse over { S*2^CSHIFT (bulk), cnt*exp(0), exp(diag) }
__device__ inline float final_lse(float S, float cntlog, float diag) {
    float l1 = (S > 0.0f) ? (CSHIFT + fast_log2(S)) * LN2F : -INFINITY;
    float M = fmaxf(fmaxf(l1, cntlog), diag);  // M finite: diag always finite
    return M + __logf(__expf(l1 - M) + __expf(cntlog - M) + __expf(diag - M));
}

// ---------------- kernel 2: per-row contribution (wave per row) ----------------
__global__ void row_contrib(const float* __restrict__ F, const float* __restrict__ Imp,
                            const float* __restrict__ partials_row,
                            const float* __restrict__ colsum,
                            const int* __restrict__ counts,
                            const int* __restrict__ labels, float* __restrict__ blockSums) {
    const int lane = threadIdx.x & 63;
    const int wave = threadIdx.x >> 6;
    const int row = blockIdx.x * 4 + wave;

    // fp32 diagonal dot: 256 floats = 64 lanes * float4
    float4 a = reinterpret_cast<const float4*>(F + (size_t)row * D)[lane];
    float4 b = reinterpret_cast<const float4*>(Imp + (size_t)row * D)[lane];
    float dot = a.x * b.x + a.y * b.y + a.z * b.z + a.w * b.w;
#pragma unroll
    for (int off = 32; off > 0; off >>= 1) dot += __shfl_xor(dot, off, 64);

    // S_row: 32 slice partials in lanes 0..31 (parallel load + reduce)
    float sr = (lane < NSLICE) ? partials_row[(size_t)row * NSLICE + lane] : 0.0f;
#pragma unroll
    for (int off = 16; off > 0; off >>= 1) sr += __shfl_xor(sr, off, 64);

    __shared__ float sums[4];
    if (lane == 0) {
        const float diag = 2.0f * dot;                 // temperature 0.5
        const int cnt = counts[labels[row]] - 1;       // equal-label count excl. self
        const float cntlog = (cnt > 0) ? __logf((float)cnt) : -INFINITY;
        const float S_col = colsum[row];
        const float lse_total = final_lse(sr, cntlog, diag) + final_lse(S_col, cntlog, diag);
        sums[wave] = 2.0f * diag - lse_total;
    }
    __syncthreads();
    if (threadIdx.x == 0)
        blockSums[blockIdx.x] = sums[0] + sums[1] + sums[2] + sums[3];
}

// ---------------- kernel 3: final deterministic reduce ----------------
__global__ void final_reduce(const float* __restrict__ blockSums, float* __restrict__ out) {
    __shared__ float red[256];
    float v = 0.0f;
    for (int i = threadIdx.x; i < N / 4; i += 256) v += blockSums[i];
    red[threadIdx.x] = v;
    __syncthreads();
    for (int st = 128; st > 0; st >>= 1) {
        if (threadIdx.x < st) red[threadIdx.x] += red[threadIdx.x + st];
        __syncthreads();
    }
    if (threadIdx.x == 0) out[0] = -red[0] / (float)N;
}

extern "C" void kernel_launch(void* const* d_in, const int* in_sizes, int n_in,
                              void* d_out, int out_size, void* d_ws, size_t ws_size,
                              hipStream_t stream) {
    const float* F = (const float*)d_in[0];
    const float* Imp = (const float*)d_in[1];
    const int* labels = (const int*)d_in[2];
    float* out = (float*)d_out;

    char* ws = (char*)d_ws;
    size_t off = 0;
    unsigned char* Fb8 = (unsigned char*)(ws + off); off += (size_t)N * D;    // 2 MB
    unsigned char* Ib8 = (unsigned char*)(ws + off); off += (size_t)N * D;    // 2 MB
    float* partials_row = (float*)(ws + off); off += (size_t)N * NSLICE * 4;  // 1 MB
    float* partials_col = (float*)(ws + off); off += (size_t)NRB * N * 4;     // 1 MB
    float* colsum = (float*)(ws + off); off += (size_t)N * 4;                 // 32 KB
    float* blockSums = (float*)(ws + off); off += (size_t)(N / 4) * 4;        // 8 KB
    int* counts = (int*)(ws + off);

    dim3 cgrid(N * D / 8 / 256, 2);  // 8 bytes per thread
    convert_fp8<<<cgrid, 256, 0, stream>>>(F, Imp, (unsigned int*)Fb8, (unsigned int*)Ib8);
    label_hist<<<1, 256, 0, stream>>>(labels, counts);

    dim3 g(NRB, NSLICE);
    tile_pass<<<g, 256, 0, stream>>>(Fb8, Ib8, labels, partials_row, partials_col);

    col_reduce<<<N / 256, 256, 0, stream>>>(partials_col, colsum);
    row_contrib<<<N / 4, 256, 0, stream>>>(F, Imp, partials_row, colsum, counts, labels, blockSums);
    final_reduce<<<1, 256, 0, stream>>>(blockSums, out);
}

// Round 12
// 64.462 us; speedup vs baseline: 2.0586x; 1.0599x over previous
//
#include <hip/hip_runtime.h>
#include <hip/hip_bf16.h>

#define N 8192
#define D 256
#define NSLICE 16
#define BM 128                          // rows per block (4 waves x 32 rows)
#define TROWS 2                         // row-tiles of 16 per wave
#define CB 32                           // cols per staged LDS tile
#define COLS_PER_SLICE (N / NSLICE)     // 512
#define NT (COLS_PER_SLICE / CB)        // 16 tiles per block
#define NRB (N / BM)                    // 64 row blocks
#define TILE_B (CB * D)                 // 8192 bytes per fp8 tile

#define CSHIFT 160.0f                   // fixed base-2 LSE shift
#define K2LOG2E 2.885390082f            // (1/T) * log2(e) = 2 * 1.44269504
#define LN2F 0.6931471805599453f

typedef __attribute__((ext_vector_type(4))) float f32x4;

__device__ inline float fast_exp2(float x) { return __builtin_amdgcn_exp2f(x); }
__device__ inline float fast_log2(float x) { return __builtin_amdgcn_logf(x); }

// async global->LDS, 16B per lane; LDS dest = wave-uniform base + lane*16.
__device__ inline void gload_lds16(const void* g, void* l) {
    __builtin_amdgcn_global_load_lds(
        (const __attribute__((address_space(1))) void*)g,
        (__attribute__((address_space(3))) void*)l, 16, 0, 0);
}

// pack 4 fp32 -> 4 fp8 e4m3 bytes (OCP on gfx950)
__device__ inline unsigned int pack_fp8x4(float a, float b, float c, float d) {
    unsigned int p = __builtin_amdgcn_cvt_pk_fp8_f32(a, b, 0, 0);    // bytes 0-1
    p = __builtin_amdgcn_cvt_pk_fp8_f32(c, d, (int)p, 1);            // bytes 2-3
    return p;
}

// ---------------- kernel 0: fp32 -> fp8 conversion ----------------
// y==0: F row-major fp8 (read directly to regs in tile_pass)
// y==1: I in FRAGMENT order: thread i (8B) -> byte off i*8 = g*4096 + ks*512
//       + lane*8, holding I[g*16 + (lane&15)][ks*32 + (lane>>4)*8 .. +7],
// so global_load_lds with LINEAR dest yields the MFMA B-fragment layout.
__global__ void convert_fp8(const float* __restrict__ F, const float* __restrict__ Imp,
                            unsigned int* __restrict__ Fb8, unsigned int* __restrict__ Ib8) {
    const int i = blockIdx.x * blockDim.x + threadIdx.x;  // 8 bytes per thread
    if (blockIdx.y == 0) {
        const float4 v0 = reinterpret_cast<const float4*>(F)[i * 2];
        const float4 v1 = reinterpret_cast<const float4*>(F)[i * 2 + 1];
        Fb8[i * 2] = pack_fp8x4(v0.x, v0.y, v0.z, v0.w);
        Fb8[i * 2 + 1] = pack_fp8x4(v1.x, v1.y, v1.z, v1.w);
    } else {
        const int lane = i & 63;
        const int ks = (i >> 6) & 7;
        const int g = i >> 9;
        const int col = g * 16 + (lane & 15);
        const int k0 = ks * 32 + (lane >> 4) * 8;
        const float* src = Imp + (size_t)col * D + k0;
        const float4 v0 = *reinterpret_cast<const float4*>(src);
        const float4 v1 = *reinterpret_cast<const float4*>(src + 4);
        Ib8[i * 2] = pack_fp8x4(v0.x, v0.y, v0.z, v0.w);
        Ib8[i * 2 + 1] = pack_fp8x4(v1.x, v1.y, v1.z, v1.w);
    }
}

// ---------------- kernel 0b: label histogram (14 bins) ----------------
__global__ void label_hist(const int* __restrict__ labels, int* __restrict__ counts) {
    __shared__ int c[16];
    if (threadIdx.x < 16) c[threadIdx.x] = 0;
    __syncthreads();
    for (int i = threadIdx.x; i < N; i += blockDim.x) atomicAdd(&c[labels[i]], 1);
    __syncthreads();
    if (threadIdx.x < 16) counts[threadIdx.x] = c[threadIdx.x];
}

// ---------------- kernel 1: fp8 single-pass tile kernel ----------------
// TROWS=2 -> afrag 32 VGPRs; total ~100 regs fits the (256,4) budget of 128
// WITHOUT the compiler sinking A-loads into the loop (r7-r11 pathology).
// 34KB LDS + 1024 blocks -> 4 blocks/CU: staggered barriers feed MFMA pipe.
// Triple-buffer, counted vmcnt, raw s_barrier, setprio.
// blockIdx.x: row block (128 rows), blockIdx.y: column slice (512 cols).
__launch_bounds__(256, 4)
__global__ void tile_pass(const unsigned char* __restrict__ Fb8,
                          const unsigned char* __restrict__ Ib8,
                          const int* __restrict__ labels,
                          float* __restrict__ partials_row,    // [N][NSLICE]
                          float* __restrict__ partials_col) {  // [NRB][N]
    __shared__ __align__(16) unsigned char Bsh[3 * TILE_B];  // 24KB
    __shared__ float colacc[4][COLS_PER_SLICE];              // 8KB
    __shared__ int labs[COLS_PER_SLICE];                     // 2KB

    const int tid = threadIdx.x;
    const int lane = tid & 63;
    const int wave = tid >> 6;
    const int rb = blockIdx.x;
    const int row0 = rb * BM + wave * (16 * TROWS);
    const int c0 = blockIdx.y * COLS_PER_SLICE;
    const int lrow = lane & 15;
    const int kgrp = lane >> 4;

    // stage one 32-col tile (8KB, fragment-ordered in GLOBAL memory):
    // 8 chunks of 1KB; wave w stages chunks 2w, 2w+1; linear dest & src.
#define STAGE(buf, ct)                                                          \
    {                                                                           \
        const unsigned char* tbase = Ib8 + (size_t)(c0 + (ct) * CB) * D;        \
        _Pragma("unroll")                                                       \
        for (int i = 0; i < 2; ++i) {                                           \
            const int chunk = wave * 2 + i;                                     \
            gload_lds16(tbase + chunk * 1024 + lane * 16,                       \
                        &Bsh[(buf) * TILE_B + chunk * 1024 + lane * 16]);       \
        }                                                                       \
    }

    STAGE(0, 0);
    STAGE(1, 1);

    for (int i = tid; i < COLS_PER_SLICE; i += 256) {
        labs[i] = labels[c0 + i];
        colacc[0][i] = 0.f; colacc[1][i] = 0.f; colacc[2][i] = 0.f; colacc[3][i] = 0.f;
    }

    // A fragments fp8: 8 bytes/lane per (t,ks) = 2 VGPRs; 32 VGPRs total.
    long afrag[TROWS][8];
#pragma unroll
    for (int t = 0; t < TROWS; ++t) {
        const unsigned char* arow = Fb8 + (size_t)(row0 + t * 16 + lrow) * D;
#pragma unroll
        for (int ks = 0; ks < 8; ++ks)
            afrag[t][ks] = *reinterpret_cast<const long*>(arow + ks * 32 + kgrp * 8);
    }

    // my output rows' labels, packed 4x8 bits per row-tile (labels 0..13)
    int labp[TROWS];
#pragma unroll
    for (int t = 0; t < TROWS; ++t) {
        const int base = row0 + t * 16 + kgrp * 4;
        labp[t] = labels[base] | (labels[base + 1] << 8) |
                  (labels[base + 2] << 16) | (labels[base + 3] << 24);
    }

    float s[TROWS][4];
#pragma unroll
    for (int t = 0; t < TROWS; ++t)
#pragma unroll
        for (int r = 0; r < 4; ++r) s[t][r] = 0.0f;

    // tile 0 landed (2 loads of tile 1 may fly); labs/colacc visible
    asm volatile("s_waitcnt vmcnt(2) lgkmcnt(0)" ::: "memory");
    __builtin_amdgcn_s_barrier();

    int cbuf = 0, sbuf = 2;
    for (int ct = 0; ct < NT; ++ct) {
        if (ct + 2 < NT) STAGE(sbuf, ct + 2);  // keep 2 tiles in flight

        __builtin_amdgcn_s_setprio(1);
#pragma unroll
        for (int u = 0; u < 2; ++u) {
            long bfrag[8];
#pragma unroll
            for (int ks = 0; ks < 8; ++ks)
                bfrag[ks] = *reinterpret_cast<const long*>(
                    &Bsh[cbuf * TILE_B + (u * 8 + ks) * 512 + lane * 8]);  // linear

            const int labc = labs[ct * CB + u * 16 + lrow];
            float colpart = 0.0f;
            f32x4 acc[TROWS];
#pragma unroll
            for (int t = 0; t < TROWS; ++t) acc[t] = f32x4{0.f, 0.f, 0.f, 0.f};
#pragma unroll
            for (int ks = 0; ks < 8; ++ks)
#pragma unroll
                for (int t = 0; t < TROWS; ++t)
                    acc[t] = __builtin_amdgcn_mfma_f32_16x16x32_fp8_fp8(
                        afrag[t][ks], bfrag[ks], acc[t], 0, 0, 0);

#pragma unroll
            for (int t = 0; t < TROWS; ++t) {
                // D layout: col = lane&15, row = (lane>>4)*4 + r (dtype-indep)
#pragma unroll
                for (int r = 0; r < 4; ++r) {
                    float arg = __builtin_fmaf(acc[t][r], K2LOG2E, -CSHIFT);
                    const int lr = (labp[t] >> (8 * r)) & 255;
                    arg = (lr == labc) ? -1000.0f : arg;  // masked (incl. diag) -> 0
                    float e = fast_exp2(arg);
                    s[t][r] += e;
                    colpart += e;
                }
            }
            colpart += __shfl_xor(colpart, 16, 64);
            colpart += __shfl_xor(colpart, 32, 64);
            if (kgrp == 0)
                colacc[wave][ct * CB + u * 16 + lrow] += colpart;
        }
        __builtin_amdgcn_s_setprio(0);

        // counted wait: tile t+1 landed, tile t+2 stays in flight
        if (ct + 2 < NT) {
            asm volatile("s_waitcnt vmcnt(2)" ::: "memory");
        } else {
            asm volatile("s_waitcnt vmcnt(0)" ::: "memory");
        }
        __builtin_amdgcn_s_barrier();
        cbuf = (cbuf == 2) ? 0 : cbuf + 1;
        sbuf = (sbuf == 2) ? 0 : sbuf + 1;
    }

    // row partials: sum the 16 lrow-lanes (disjoint column subsets)
#pragma unroll
    for (int off = 1; off < 16; off <<= 1) {
#pragma unroll
        for (int t = 0; t < TROWS; ++t)
#pragma unroll
            for (int r = 0; r < 4; ++r)
                s[t][r] += __shfl_xor(s[t][r], off, 64);
    }
    if (lrow == 0) {
#pragma unroll
        for (int t = 0; t < TROWS; ++t)
#pragma unroll
            for (int r = 0; r < 4; ++r) {
                const int grow = row0 + t * 16 + kgrp * 4 + r;
                partials_row[(size_t)grow * NSLICE + blockIdx.y] = s[t][r];
            }
    }

    __syncthreads();  // all colacc writes visible
    for (int i = tid; i < COLS_PER_SLICE; i += 256) {
        float v = colacc[0][i] + colacc[1][i] + colacc[2][i] + colacc[3][i];
        partials_col[(size_t)rb * N + c0 + i] = v;
    }
#undef STAGE
}

// ---------------- kernel 1b: reduce col partials over row blocks ----------------
__global__ void col_reduce(const float* __restrict__ partials_col, float* __restrict__ colsum) {
    const int c = blockIdx.x * 256 + threadIdx.x;
    float v = 0.0f;
    for (int rbi = 0; rbi < NRB; ++rbi) v += partials_col[(size_t)rbi * N + c];
    colsum[c] = v;
}

// exact lse over { S*2^CSHIFT (bulk), cnt*exp(0), exp(diag) }
__device__ inline float final_lse(float S, float cntlog, float diag) {
    float l1 = (S > 0.0f) ? (CSHIFT + fast_log2(S)) * LN2F : -INFINITY;
    float M = fmaxf(fmaxf(l1, cntlog), diag);  // M finite: diag always finite
    return M + __logf(__expf(l1 - M) + __expf(cntlog - M) + __expf(diag - M));
}

// ---------------- kernel 2: per-row contribution (wave per row) ----------------
__global__ void row_contrib(const float* __restrict__ F, const float* __restrict__ Imp,
                            const float* __restrict__ partials_row,
                            const float* __restrict__ colsum,
                            const int* __restrict__ counts,
                            const int* __restrict__ labels, float* __restrict__ blockSums) {
    const int lane = threadIdx.x & 63;
    const int wave = threadIdx.x >> 6;
    const int row = blockIdx.x * 4 + wave;

    // fp32 diagonal dot: 256 floats = 64 lanes * float4
    float4 a = reinterpret_cast<const float4*>(F + (size_t)row * D)[lane];
    float4 b = reinterpret_cast<const float4*>(Imp + (size_t)row * D)[lane];
    float dot = a.x * b.x + a.y * b.y + a.z * b.z + a.w * b.w;
#pragma unroll
    for (int off = 32; off > 0; off >>= 1) dot += __shfl_xor(dot, off, 64);

    // S_row: NSLICE partials in lanes 0..NSLICE-1 (zeros elsewhere)
    float sr = (lane < NSLICE) ? partials_row[(size_t)row * NSLICE + lane] : 0.0f;
#pragma unroll
    for (int off = 16; off > 0; off >>= 1) sr += __shfl_xor(sr, off, 64);

    __shared__ float sums[4];
    if (lane == 0) {
        const float diag = 2.0f * dot;                 // temperature 0.5
        const int cnt = counts[labels[row]] - 1;       // equal-label count excl. self
        const float cntlog = (cnt > 0) ? __logf((float)cnt) : -INFINITY;
        const float S_col = colsum[row];
        const float lse_total = final_lse(sr, cntlog, diag) + final_lse(S_col, cntlog, diag);
        sums[wave] = 2.0f * diag - lse_total;
    }
    __syncthreads();
    if (threadIdx.x == 0)
        blockSums[blockIdx.x] = sums[0] + sums[1] + sums[2] + sums[3];
}

// ---------------- kernel 3: final deterministic reduce ----------------
__global__ void final_reduce(const float* __restrict__ blockSums, float* __restrict__ out) {
    __shared__ float red[256];
    float v = 0.0f;
    for (int i = threadIdx.x; i < N / 4; i += 256) v += blockSums[i];
    red[threadIdx.x] = v;
    __syncthreads();
    for (int st = 128; st > 0; st >>= 1) {
        if (threadIdx.x < st) red[threadIdx.x] += red[threadIdx.x + st];
        __syncthreads();
    }
    if (threadIdx.x == 0) out[0] = -red[0] / (float)N;
}

extern "C" void kernel_launch(void* const* d_in, const int* in_sizes, int n_in,
                              void* d_out, int out_size, void* d_ws, size_t ws_size,
                              hipStream_t stream) {
    const float* F = (const float*)d_in[0];
    const float* Imp = (const float*)d_in[1];
    const int* labels = (const int*)d_in[2];
    float* out = (float*)d_out;

    char* ws = (char*)d_ws;
    size_t off = 0;
    unsigned char* Fb8 = (unsigned char*)(ws + off); off += (size_t)N * D;    // 2 MB
    unsigned char* Ib8 = (unsigned char*)(ws + off); off += (size_t)N * D;    // 2 MB
    float* partials_row = (float*)(ws + off); off += (size_t)N * NSLICE * 4;  // 512 KB
    float* partials_col = (float*)(ws + off); off += (size_t)NRB * N * 4;     // 2 MB
    float* colsum = (float*)(ws + off); off += (size_t)N * 4;                 // 32 KB
    float* blockSums = (float*)(ws + off); off += (size_t)(N / 4) * 4;        // 8 KB
    int* counts = (int*)(ws + off);

    dim3 cgrid(N * D / 8 / 256, 2);  // 8 bytes per thread
    convert_fp8<<<cgrid, 256, 0, stream>>>(F, Imp, (unsigned int*)Fb8, (unsigned int*)Ib8);
    label_hist<<<1, 256, 0, stream>>>(labels, counts);

    dim3 g(NRB, NSLICE);
    tile_pass<<<g, 256, 0, stream>>>(Fb8, Ib8, labels, partials_row, partials_col);

    col_reduce<<<N / 256, 256, 0, stream>>>(partials_col, colsum);
    row_contrib<<<N / 4, 256, 0, stream>>>(F, Imp, partials_row, colsum, counts, labels, blockSums);
    final_reduce<<<1, 256, 0, stream>>>(blockSums, out);
}